// Round 12
// baseline (22372.368 us; speedup 1.0000x reference)
//
#include <hip/hip_runtime.h>
#include <hip/hip_cooperative_groups.h>
#include <cstddef>

namespace cg = cooperative_groups;

typedef _Float16 f16;
typedef unsigned int u32;
typedef __attribute__((ext_vector_type(8))) _Float16 half8;
typedef __attribute__((ext_vector_type(4))) _Float16 half4;
typedef __attribute__((ext_vector_type(4))) float f32x4;

#define BATCH 256
#define CH    32
#define LR    64
#define UNITS 128
#define DIN   416
#define NC    1024
#define KU    384

// ---- ws byte offsets (total 93,982,720 == proven size) --------------------
#define OFF_WH   0ull                      // f16 [896][416]  Wcat^T hi (wr|wz)
#define OFF_WL   745472ull                 // f16 [896][416]  lo
#define OFF_W3H  1490944ull                // f16 [128][32]   w_ij block hi
#define OFF_W3L  1499136ull                // lo
#define OFF_BC   1507328ull                // f32 [1024] bias
#define OFF_UH   1511424ull                // f16 [128][384]  U^T hi
#define OFF_UL   1609728ull                // lo
#define OFF_HHI  1708032ull                // f16 [3][64][256][128] h hi planes
#define HPLANE   4194304ull                // bytes per slot plane
#define OFF_HLO  (OFF_HHI + 3ull*HPLANE)   // h lo planes
#define OFF_G    (OFF_HLO + 3ull*HPLANE)   // f32 [64][256][1024]

static __device__ __forceinline__ void gll16(const void* g, void* l) {
  __builtin_amdgcn_global_load_lds(
      (const __attribute__((address_space(1))) u32*)g,
      (__attribute__((address_space(3))) u32*)l, 16, 0, 0);
}
static __device__ __forceinline__ float fast_tanh(float x) {
  float e = __expf(-2.f * fabsf(x));
  float t = (1.f - e) / (1.f + e);
  return copysignf(t, x);
}

// ---------------------------------------------------------------------------
// One persistent cooperative kernel: prep -> 127x (gemm phase | sync | gate
// phase | sync) -> output copy. Tile bodies are byte-identical to R6 kernels.
// ---------------------------------------------------------------------------
__global__ __launch_bounds__(256, 2) void fused_kernel(
    const float* __restrict__ inputs,
    const float* __restrict__ wr, const float* __restrict__ br,
    const float* __restrict__ wz, const float* __restrict__ bz,
    const float* __restrict__ w_ij, const float* __restrict__ b_ij,
    const float* __restrict__ Umat, char* __restrict__ ws,
    float* __restrict__ out) {
  cg::grid_group grid = cg::this_grid();
  const int bid = blockIdx.x, nblk = gridDim.x, t = threadIdx.x;
  const int w = t >> 6, lane = t & 63;
  const int lm = lane & 15, ksl = lane >> 4;

  __shared__ f16 smA[4096], smB[4096], smC[4096], smD[4096];   // 32 KB

  // staging constants (shared by both phases)
  const int s0 = w * 128 + lane, s1 = s0 + 64;
  const int r0s = s0 >> 2, k0s = (s0 & 3) ^ ((r0s >> 1) & 3);
  const int r1s = s1 >> 2, k1s = (s1 & 3) ^ ((r1s >> 1) & 3);
  const u32 db0 = (u32)w * 2048u, db1 = db0 + 1024u;
  const int kswz = (ksl ^ ((lm >> 1) & 3)) * 8;

  // ===== prep =====
  for (int idx = bid * 256 + t; idx < 896 * DIN; idx += nblk * 256) {
    {
      int n = idx / DIN, k = idx % DIN;
      float v = (n < 384) ? wr[k * 384 + n] : wz[k * 512 + (n - 384)];
      f16 hi = (f16)v;
      ((f16*)(ws + OFF_WH))[idx] = hi;
      ((f16*)(ws + OFF_WL))[idx] = (f16)(v - (float)hi);
    }
    if (idx < 128 * 32) {
      int n3 = idx >> 5, k3 = idx & 31;
      float v = w_ij[k3 * UNITS + n3];
      f16 hi = (f16)v;
      ((f16*)(ws + OFF_W3H))[idx] = hi;
      ((f16*)(ws + OFF_W3L))[idx] = (f16)(v - (float)hi);
    }
    if (idx < UNITS * KU) {
      int n = idx / KU, k = idx % KU;
      float v = Umat[k * UNITS + n];
      f16 hi = (f16)v;
      ((f16*)(ws + OFF_UH))[idx] = hi;
      ((f16*)(ws + OFF_UL))[idx] = (f16)(v - (float)hi);
    }
    if (idx < NC) {
      float b;
      if (idx < 384)      b = br[idx];
      else if (idx < 896) b = bz[idx - 384];
      else                b = b_ij[idx - 896];
      ((float*)(ws + OFF_BC))[idx] = b;
    }
  }
  grid.sync();

  const f16* __restrict__ Wh  = (const f16*)(ws + OFF_WH);
  const f16* __restrict__ Wl  = (const f16*)(ws + OFF_WL);
  const f16* __restrict__ W3h = (const f16*)(ws + OFF_W3H);
  const f16* __restrict__ W3l = (const f16*)(ws + OFF_W3L);
  const f16* __restrict__ UhT = (const f16*)(ws + OFF_UH);
  const f16* __restrict__ UlT = (const f16*)(ws + OFF_UL);
  const float* __restrict__ bc = (const float*)(ws + OFF_BC);

  for (int d = 0; d < 127; d++) {
    const int i0 = d > 63 ? d - 63 : 0;
    const int i1d = d < 63 ? d : 63;
    const int nc = i1d - i0 + 1;
    const f16* __restrict__ H1h = (const f16*)(ws + OFF_HHI + (size_t)((d + 2) % 3) * HPLANE);
    const f16* __restrict__ H1l = (const f16*)(ws + OFF_HLO + (size_t)((d + 2) % 3) * HPLANE);
    const f16* __restrict__ H2h = (const f16*)(ws + OFF_HHI + (size_t)((d + 1) % 3) * HPLANE);
    const f16* __restrict__ H2l = (const f16*)(ws + OFF_HLO + (size_t)((d + 1) % 3) * HPLANE);
    f16* __restrict__ Hoh = (f16*)(ws + OFF_HHI + (size_t)(d % 3) * HPLANE);
    f16* __restrict__ Hol = (f16*)(ws + OFF_HLO + (size_t)(d % 3) * HPLANE);

    // ===== gemm phase: G = q @ Wcat + bias (3-term f16 split) =====
    for (int tt = bid; tt < nc * 16; tt += nblk) {
      const int cb = tt & 7, rb = (tt >> 3) & 1, ci = tt >> 4;
      const int i = i0 + ci, j = d - i;
      const int b0 = rb * 128, n0 = cb * 128;
      const int wrow = (w >> 1) * 64, wcol = (w & 1) * 64;
      const bool vt = (i > 0), vl = (j > 0), vd = (i > 0 && j > 0);
      f16* const Ah = smA; f16* const Al = smB;
      f16* const Bh = smC; f16* const Bl = smD;

      f32x4 acc[4][4];
#pragma unroll
      for (int mi = 0; mi < 4; mi++)
#pragma unroll
        for (int ni = 0; ni < 4; ni++)
#pragma unroll
          for (int r = 0; r < 4; r++) acc[mi][ni][r] = 0.f;

      for (int kt = (cb == 7 ? 12 : 0); kt < 13; kt++) {
        const bool ok = (kt < 4) ? vt : (kt < 8) ? vl : (kt < 12) ? vd : true;
        if (!ok) continue;

        if (kt < 12) {   // A from h planes (DMA)
          const f16 *ph, *pl; int hrow;
          if (kt < 4)      { ph = H1h; pl = H1l; hrow = i - 1; }   // h_top
          else if (kt < 8) { ph = H1h; pl = H1l; hrow = i; }       // h_left
          else             { ph = H2h; pl = H2l; hrow = i - 1; }   // h_diag
          const size_t ab = ((size_t)hrow * BATCH + b0) * UNITS + (size_t)(kt & 3) * 32;
          gll16(ph + ab + r0s * UNITS + k0s * 8, (char*)Ah + db0);
          gll16(ph + ab + r1s * UNITS + k1s * 8, (char*)Ah + db1);
          gll16(pl + ab + r0s * UNITS + k0s * 8, (char*)Al + db0);
          gll16(pl + ab + r1s * UNITS + k1s * 8, (char*)Al + db1);
        } else {         // A = s_ij gather (swizzled ds_write)
          const int r = t >> 1, kp = (t & 1) * 2;
          const int b = b0 + r, sw = (r >> 1) & 3;
#pragma unroll
          for (int c2 = 0; c2 < 2; c2++) {
            const int c = kp + c2;
            half8 hv, lv;
#pragma unroll
            for (int q = 0; q < 8; q++) {
              float v = inputs[((size_t)b * CH + c * 8 + q) * (LR * LR) + i * LR + j];
              f16 h = (f16)v;
              hv[q] = h; lv[q] = (f16)(v - (float)h);
            }
            const int p = r * 4 + (c ^ sw);
            *(half8*)&Ah[p * 8] = hv;
            *(half8*)&Al[p * 8] = lv;
          }
        }
        if (cb < 7) {
          const size_t bb = (size_t)n0 * DIN + (size_t)kt * 32;
          gll16(Wh + bb + r0s * DIN + k0s * 8, (char*)Bh + db0);
          gll16(Wh + bb + r1s * DIN + k1s * 8, (char*)Bh + db1);
          gll16(Wl + bb + r0s * DIN + k0s * 8, (char*)Bl + db0);
          gll16(Wl + bb + r1s * DIN + k1s * 8, (char*)Bl + db1);
        } else {
          gll16(W3h + r0s * 32 + k0s * 8, (char*)Bh + db0);
          gll16(W3h + r1s * 32 + k1s * 8, (char*)Bh + db1);
          gll16(W3l + r0s * 32 + k0s * 8, (char*)Bl + db0);
          gll16(W3l + r1s * 32 + k1s * 8, (char*)Bl + db1);
        }
        __syncthreads();

        half8 afh[4], afl[4], bfh[4], bfl[4];
#pragma unroll
        for (int mi = 0; mi < 4; mi++) {
          const int ro = (wrow + mi * 16 + lm) * 32 + kswz;
          afh[mi] = *(const half8*)&Ah[ro];
          afl[mi] = *(const half8*)&Al[ro];
        }
#pragma unroll
        for (int ni = 0; ni < 4; ni++) {
          const int ro = (wcol + ni * 16 + lm) * 32 + kswz;
          bfh[ni] = *(const half8*)&Bh[ro];
          bfl[ni] = *(const half8*)&Bl[ro];
        }
#pragma unroll
        for (int mi = 0; mi < 4; mi++)
#pragma unroll
          for (int ni = 0; ni < 4; ni++) {
            acc[mi][ni] = __builtin_amdgcn_mfma_f32_16x16x32_f16(afh[mi], bfh[ni], acc[mi][ni], 0, 0, 0);
            acc[mi][ni] = __builtin_amdgcn_mfma_f32_16x16x32_f16(afl[mi], bfh[ni], acc[mi][ni], 0, 0, 0);
            acc[mi][ni] = __builtin_amdgcn_mfma_f32_16x16x32_f16(afh[mi], bfl[ni], acc[mi][ni], 0, 0, 0);
          }
        __syncthreads();
      }

      float* __restrict__ G = (float*)(ws + OFF_G) + (size_t)ci * BATCH * NC;
#pragma unroll
      for (int mi = 0; mi < 4; mi++)
#pragma unroll
        for (int ni = 0; ni < 4; ni++) {
          const int n = n0 + wcol + ni * 16 + lm;
          const float bb = bc[n];
#pragma unroll
          for (int r = 0; r < 4; r++) {
            const int b = b0 + wrow + mi * 16 + ksl * 4 + r;
            G[(size_t)b * NC + n] = acc[mi][ni][r] + bb;
          }
        }
    }
    grid.sync();

    // ===== gate phase =====
    for (int tt = bid; tt < nc * 8; tt += nblk) {
      const int rb = tt & 7, ci = tt >> 3;
      const int i = i0 + ci, j = d - i;
      const int b0 = rb * 32;
      const int wcol = w * 32;
      const bool vt = (i > 0), vlf = (j > 0), vd = (i > 0 && j > 0);
      f16 (* const Rh)[40] = (f16(*)[40])smA;
      f16 (* const Rl)[40] = (f16(*)[40])smB;
      f16* const Uh = smC; f16* const Ul = smD;

      float* __restrict__ G = (float*)(ws + OFF_G) + (size_t)ci * BATCH * NC;

      f32x4 acc[2][2];
#pragma unroll
      for (int mi = 0; mi < 2; mi++)
#pragma unroll
        for (int ni = 0; ni < 2; ni++)
#pragma unroll
          for (int r = 0; r < 4; r++) acc[mi][ni][r] = 0.f;

      const int sr = t >> 3, sk = (t & 7) * 4;

      for (int kt = 0; kt < 12; kt++) {
        const f16 *ph, *pl; int hrow; bool ok;
        if (kt < 4)      { ph = H1h; pl = H1l; hrow = i;     ok = vlf; }  // h_left
        else if (kt < 8) { ph = H1h; pl = H1l; hrow = i - 1; ok = vt; }   // h_top
        else             { ph = H2h; pl = H2l; hrow = i - 1; ok = vd; }   // h_diag
        if (!ok) continue;
        {
          const int b = b0 + sr;
          const f32x4 g = *(const f32x4*)&G[(size_t)b * NC + kt * 32 + sk];
          const size_t hx = ((size_t)hrow * BATCH + b) * UNITS + (kt & 3) * 32 + sk;
          const half4 h4 = *(const half4*)(ph + hx);
          const half4 l4 = *(const half4*)(pl + hx);
          half4 oh, ol;
#pragma unroll
          for (int q = 0; q < 4; q++) {
            const float rv = 1.f / (1.f + __expf(-g[q]));
            const float v = rv * ((float)h4[q] + (float)l4[q]);
            const f16 h = (f16)v;
            oh[q] = h; ol[q] = (f16)(v - (float)h);
          }
          *(half4*)&Rh[sr][sk] = oh;
          *(half4*)&Rl[sr][sk] = ol;
        }
        {
          const size_t ub = (size_t)kt * 32;
          gll16(UhT + ub + r0s * KU + k0s * 8, (char*)Uh + db0);
          gll16(UhT + ub + r1s * KU + k1s * 8, (char*)Uh + db1);
          gll16(UlT + ub + r0s * KU + k0s * 8, (char*)Ul + db0);
          gll16(UlT + ub + r1s * KU + k1s * 8, (char*)Ul + db1);
        }
        __syncthreads();

        half8 afh[2], afl[2], bfh[2], bfl[2];
#pragma unroll
        for (int mi = 0; mi < 2; mi++) {
          afh[mi] = *(const half8*)&Rh[mi * 16 + lm][ksl * 8];
          afl[mi] = *(const half8*)&Rl[mi * 16 + lm][ksl * 8];
        }
#pragma unroll
        for (int ni = 0; ni < 2; ni++) {
          const int ro = (wcol + ni * 16 + lm) * 32 + kswz;
          bfh[ni] = *(const half8*)&Uh[ro];
          bfl[ni] = *(const half8*)&Ul[ro];
        }
#pragma unroll
        for (int mi = 0; mi < 2; mi++)
#pragma unroll
          for (int ni = 0; ni < 2; ni++) {
            acc[mi][ni] = __builtin_amdgcn_mfma_f32_16x16x32_f16(afh[mi], bfh[ni], acc[mi][ni], 0, 0, 0);
            acc[mi][ni] = __builtin_amdgcn_mfma_f32_16x16x32_f16(afl[mi], bfh[ni], acc[mi][ni], 0, 0, 0);
            acc[mi][ni] = __builtin_amdgcn_mfma_f32_16x16x32_f16(afh[mi], bfl[ni], acc[mi][ni], 0, 0, 0);
          }
        __syncthreads();
      }

      // epilogue
#pragma unroll
      for (int mi = 0; mi < 2; mi++)
#pragma unroll
        for (int r = 0; r < 4; r++) {
          const int b = b0 + mi * 16 + ksl * 4 + r;
          const float* __restrict__ Gr = G + (size_t)b * NC;
          const size_t ho  = ((size_t)i * BATCH + b) * UNITS;
          const size_t htb = ((size_t)(i - 1) * BATCH + b) * UNITS;
#pragma unroll
          for (int ni = 0; ni < 2; ni++) {
            const int u = wcol + ni * 16 + lm;
            const float zi = Gr[384 + u], zl = Gr[512 + u], zt = Gr[640 + u], zd = Gr[768 + u];
            const float mm = fmaxf(fmaxf(zi, zl), fmaxf(zt, zd));
            const float ei = __expf(zi - mm), el = __expf(zl - mm),
                        et = __expf(zt - mm), ed = __expf(zd - mm);
            const float inv = 1.f / (ei + el + et + ed);
            const float hl = vlf ? (float)H1h[ho + u] + (float)H1l[ho + u] : 0.f;
            const float ht = vt  ? (float)H1h[htb + u] + (float)H1l[htb + u] : 0.f;
            const float hd = vd  ? (float)H2h[htb + u] + (float)H2l[htb + u] : 0.f;
            const float hh = fast_tanh(Gr[896 + u] + acc[mi][ni][r]);
            const float h = (el * hl + et * ht + ed * hd + ei * hh) * inv;
            const f16 hhi = (f16)h;
            Hoh[ho + u] = hhi;
            Hol[ho + u] = (f16)(h - (float)hhi);
          }
        }
    }
    grid.sync();
  }

  // ===== output: h(63,63) is in slot 126%3==0, row 63 =====
  for (int idx = bid * 256 + t; idx < BATCH * UNITS; idx += nblk * 256) {
    const f16* Hh = (const f16*)(ws + OFF_HHI);
    const f16* Hl = (const f16*)(ws + OFF_HLO);
    const size_t o = (size_t)63 * BATCH * UNITS + idx;
    out[idx] = (float)Hh[o] + (float)Hl[o];
  }
}

// ---------------------------------------------------------------------------
extern "C" void kernel_launch(void* const* d_in, const int* in_sizes, int n_in,
                              void* d_out, int out_size, void* d_ws, size_t ws_size,
                              hipStream_t stream) {
  const float* inputs = (const float*)d_in[0];
  const float* wr     = (const float*)d_in[1];
  const float* br     = (const float*)d_in[2];
  const float* wz     = (const float*)d_in[3];
  const float* bz     = (const float*)d_in[4];
  const float* w_ij   = (const float*)d_in[5];
  const float* b_ij   = (const float*)d_in[6];
  const float* Umat   = (const float*)d_in[7];
  char* ws  = (char*)d_ws;
  float* out = (float*)d_out;

  int maxPerCU = 0;
  if (hipOccupancyMaxActiveBlocksPerMultiprocessor(&maxPerCU, fused_kernel, 256, 0)
          != hipSuccess || maxPerCU < 1)
    maxPerCU = 1;
  if (maxPerCU > 4) maxPerCU = 4;      // >1024 blocks is never useful (max 1024 tiles)
  int nblk = maxPerCU * 256;           // 256 CUs on MI355X

  void* args[] = {(void*)&inputs, (void*)&wr, (void*)&br, (void*)&wz, (void*)&bz,
                  (void*)&w_ij, (void*)&b_ij, (void*)&Umat, (void*)&ws, (void*)&out};
  hipLaunchCooperativeKernel((const void*)fused_kernel, dim3(nblk), dim3(256),
                             args, 0, stream);
}

// Round 14
// 13369.994 us; speedup vs baseline: 1.6733x; 1.6733x over previous
//
#include <hip/hip_runtime.h>
#include <cstddef>

typedef _Float16 f16;
typedef unsigned int u32;
typedef __attribute__((ext_vector_type(8))) _Float16 half8;
typedef __attribute__((ext_vector_type(4))) _Float16 half4;
typedef __attribute__((ext_vector_type(4))) float f32x4;

#define BATCH 256
#define CH    32
#define LR    64
#define UNITS 128
#define DIN   416
#define NC    1024
#define KU    384

// ---- ws byte offsets (total 93,982,720 == proven size) --------------------
#define OFF_WH   0ull                      // f16 [896][416]  Wcat^T hi (wr|wz)
#define OFF_WL   745472ull                 // f16 [896][416]  lo
#define OFF_W3H  1490944ull                // f16 [128][32]   w_ij block hi
#define OFF_W3L  1499136ull                // lo
#define OFF_BC   1507328ull                // f32 [1024] bias
#define OFF_UH   1511424ull                // f16 [128][384]  U^T hi
#define OFF_UL   1609728ull                // lo
#define OFF_HHI  1708032ull                // f16 [3][64][256][128] h hi planes
#define HPLANE   4194304ull                // bytes per slot plane
#define OFF_HLO  (OFF_HHI + 3ull*HPLANE)   // h lo planes
#define OFF_G    (OFF_HLO + 3ull*HPLANE)   // f32 [64][256][1024]

static __device__ __forceinline__ void gll16(const void* g, void* l) {
  __builtin_amdgcn_global_load_lds(
      (const __attribute__((address_space(1))) u32*)g,
      (__attribute__((address_space(3))) u32*)l, 16, 0, 0);
}
static __device__ __forceinline__ float fast_tanh(float x) {
  float e = __expf(-2.f * fabsf(x));
  float t = (1.f - e) / (1.f + e);
  return copysignf(t, x);
}

// ---------------------------------------------------------------------------
__global__ __launch_bounds__(256) void prep_kernel(
    const float* __restrict__ wr, const float* __restrict__ br,
    const float* __restrict__ wz, const float* __restrict__ bz,
    const float* __restrict__ w_ij, const float* __restrict__ b_ij,
    const float* __restrict__ U, char* __restrict__ ws) {
  int idx = blockIdx.x * 256 + threadIdx.x;
  if (idx < 896 * DIN) {                       // main W: [n][k], n<896
    int n = idx / DIN, k = idx % DIN;
    float v = (n < 384) ? wr[k * 384 + n] : wz[k * 512 + (n - 384)];
    f16 hi = (f16)v;
    ((f16*)(ws + OFF_WH))[idx] = hi;
    ((f16*)(ws + OFF_WL))[idx] = (f16)(v - (float)hi);
  }
  if (idx < 128 * 32) {                        // w_ij block [n3][k3]
    int n3 = idx >> 5, k3 = idx & 31;
    float v = w_ij[k3 * UNITS + n3];
    f16 hi = (f16)v;
    ((f16*)(ws + OFF_W3H))[idx] = hi;
    ((f16*)(ws + OFF_W3L))[idx] = (f16)(v - (float)hi);
  }
  if (idx < UNITS * KU) {                      // U^T [n][k]
    int n = idx / KU, k = idx % KU;
    float v = U[k * UNITS + n];
    f16 hi = (f16)v;
    ((f16*)(ws + OFF_UH))[idx] = hi;
    ((f16*)(ws + OFF_UL))[idx] = (f16)(v - (float)hi);
  }
  if (idx < NC) {
    float b;
    if (idx < 384)      b = br[idx];
    else if (idx < 896) b = bz[idx - 384];
    else                b = b_ij[idx - 896];
    ((float*)(ws + OFF_BC))[idx] = b;
  }
}

// ---------------------------------------------------------------------------
// GEMM: G = q @ Wcat + bias (3-term f16 split). 128x128 tile, 4 waves.
// Grid: (nc, 16) with x = cell -> blocks of one cell co-locate on one XCD
// (bid%8 == ci%8 when nc%8==0): A re-reads & G become same-L2 hits.
// ---------------------------------------------------------------------------
__global__ __launch_bounds__(256, 4) void gemm_kernel(
    const float* __restrict__ inputs, char* __restrict__ ws, int d, int i0) {
  const int ci = blockIdx.x;
  const int cb = blockIdx.y & 7, rb = blockIdx.y >> 3;
  const int i = i0 + ci, j = d - i;
  const int b0 = rb * 128, n0 = cb * 128;
  const int t = threadIdx.x;
  const int w = t >> 6, lane = t & 63;
  const int lm = lane & 15, ksl = lane >> 4;
  const int wrow = (w >> 1) * 64, wcol = (w & 1) * 64;

  __shared__ f16 Ah[4096], Al[4096], Bh[4096], Bl[4096];   // 8 KB each, linear

  const int s0 = w * 128 + lane, s1 = s0 + 64;
  const int r0s = s0 >> 2, k0s = (s0 & 3) ^ ((r0s >> 1) & 3);
  const int r1s = s1 >> 2, k1s = (s1 & 3) ^ ((r1s >> 1) & 3);
  const u32 db0 = (u32)w * 2048u, db1 = db0 + 1024u;
  const int kswz = (ksl ^ ((lm >> 1) & 3)) * 8;

  const f16* __restrict__ H1h = (const f16*)(ws + OFF_HHI + (size_t)((d + 2) % 3) * HPLANE);
  const f16* __restrict__ H1l = (const f16*)(ws + OFF_HLO + (size_t)((d + 2) % 3) * HPLANE);
  const f16* __restrict__ H2h = (const f16*)(ws + OFF_HHI + (size_t)((d + 1) % 3) * HPLANE);
  const f16* __restrict__ H2l = (const f16*)(ws + OFF_HLO + (size_t)((d + 1) % 3) * HPLANE);
  const f16* __restrict__ Wh  = (const f16*)(ws + OFF_WH);
  const f16* __restrict__ Wl  = (const f16*)(ws + OFF_WL);
  const f16* __restrict__ W3h = (const f16*)(ws + OFF_W3H);
  const f16* __restrict__ W3l = (const f16*)(ws + OFF_W3L);
  const bool vt = (i > 0), vl = (j > 0), vd = (i > 0 && j > 0);

  f32x4 acc[4][4];
#pragma unroll
  for (int mi = 0; mi < 4; mi++)
#pragma unroll
    for (int ni = 0; ni < 4; ni++)
#pragma unroll
      for (int r = 0; r < 4; r++) acc[mi][ni][r] = 0.f;

  for (int kt = (cb == 7 ? 12 : 0); kt < 13; kt++) {
    const bool ok = (kt < 4) ? vt : (kt < 8) ? vl : (kt < 12) ? vd : true;
    if (!ok) continue;                                     // q is zero there

    if (kt < 12) {   // ---- A from h planes (pure DMA)
      const f16 *ph, *pl; int hrow;
      if (kt < 4)      { ph = H1h; pl = H1l; hrow = i - 1; }   // h_top
      else if (kt < 8) { ph = H1h; pl = H1l; hrow = i; }       // h_left
      else             { ph = H2h; pl = H2l; hrow = i - 1; }   // h_diag
      const size_t ab = ((size_t)hrow * BATCH + b0) * UNITS + (size_t)(kt & 3) * 32;
      gll16(ph + ab + r0s * UNITS + k0s * 8, (char*)Ah + db0);
      gll16(ph + ab + r1s * UNITS + k1s * 8, (char*)Ah + db1);
      gll16(pl + ab + r0s * UNITS + k0s * 8, (char*)Al + db0);
      gll16(pl + ab + r1s * UNITS + k1s * 8, (char*)Al + db1);
    } else {         // ---- A = s_ij gather (1 of 13 tiles), swizzled ds_write
      const int r = t >> 1, kp = (t & 1) * 2;
      const int b = b0 + r, sw = (r >> 1) & 3;
#pragma unroll
      for (int c2 = 0; c2 < 2; c2++) {
        const int c = kp + c2;
        half8 hv, lv;
#pragma unroll
        for (int q = 0; q < 8; q++) {
          float v = inputs[((size_t)b * CH + c * 8 + q) * (LR * LR) + i * LR + j];
          f16 h = (f16)v;
          hv[q] = h; lv[q] = (f16)(v - (float)h);
        }
        const int p = r * 4 + (c ^ sw);
        *(half8*)&Ah[p * 8] = hv;
        *(half8*)&Al[p * 8] = lv;
      }
    }
    // ---- B staging
    if (cb < 7) {
      const size_t bb = (size_t)n0 * DIN + (size_t)kt * 32;
      gll16(Wh + bb + r0s * DIN + k0s * 8, (char*)Bh + db0);
      gll16(Wh + bb + r1s * DIN + k1s * 8, (char*)Bh + db1);
      gll16(Wl + bb + r0s * DIN + k0s * 8, (char*)Bl + db0);
      gll16(Wl + bb + r1s * DIN + k1s * 8, (char*)Bl + db1);
    } else {         // kt==12 only; [128][32] layout
      gll16(W3h + r0s * 32 + k0s * 8, (char*)Bh + db0);
      gll16(W3h + r1s * 32 + k1s * 8, (char*)Bh + db1);
      gll16(W3l + r0s * 32 + k0s * 8, (char*)Bl + db0);
      gll16(W3l + r1s * 32 + k1s * 8, (char*)Bl + db1);
    }
    __syncthreads();

    half8 afh[4], afl[4], bfh[4], bfl[4];
#pragma unroll
    for (int mi = 0; mi < 4; mi++) {
      const int ro = (wrow + mi * 16 + lm) * 32 + kswz;
      afh[mi] = *(const half8*)&Ah[ro];
      afl[mi] = *(const half8*)&Al[ro];
    }
#pragma unroll
    for (int ni = 0; ni < 4; ni++) {
      const int ro = (wcol + ni * 16 + lm) * 32 + kswz;
      bfh[ni] = *(const half8*)&Bh[ro];
      bfl[ni] = *(const half8*)&Bl[ro];
    }
#pragma unroll
    for (int mi = 0; mi < 4; mi++)
#pragma unroll
      for (int ni = 0; ni < 4; ni++) {
        acc[mi][ni] = __builtin_amdgcn_mfma_f32_16x16x32_f16(afh[mi], bfh[ni], acc[mi][ni], 0, 0, 0);
        acc[mi][ni] = __builtin_amdgcn_mfma_f32_16x16x32_f16(afl[mi], bfh[ni], acc[mi][ni], 0, 0, 0);
        acc[mi][ni] = __builtin_amdgcn_mfma_f32_16x16x32_f16(afh[mi], bfl[ni], acc[mi][ni], 0, 0, 0);
      }
    __syncthreads();
  }

  float* __restrict__ G = (float*)(ws + OFF_G) + (size_t)ci * BATCH * NC;
  const float* __restrict__ bc = (const float*)(ws + OFF_BC);
#pragma unroll
  for (int mi = 0; mi < 4; mi++)
#pragma unroll
    for (int ni = 0; ni < 4; ni++) {
      const int n = n0 + wcol + ni * 16 + lm;
      const float bb = bc[n];
#pragma unroll
      for (int r = 0; r < 4; r++) {
        const int b = b0 + wrow + mi * 16 + ksl * 4 + r;
        G[(size_t)b * NC + n] = acc[mi][ni][r] + bb;
      }
    }
}

// ---------------------------------------------------------------------------
// Gate: rh = sigmoid(G[:, :384]) * [h_left|h_top|h_diag]; M = rh@U (3-term);
// h = softmax4(z) ⊙ {hl,ht,hd,tanh(Gs+M)}. Block: 32 rows x 128 cols, 4 waves.
// Grid: (nc, 8) with x = cell (same XCD co-location as gemm).
// ---------------------------------------------------------------------------
__global__ __launch_bounds__(256, 4) void gate_kernel(char* __restrict__ ws, int d, int i0) {
  const int ci = blockIdx.x;
  const int rb = blockIdx.y;
  const int i = i0 + ci, j = d - i;
  const int b0 = rb * 32;
  const int t = threadIdx.x;
  const int w = t >> 6, lane = t & 63;
  const int lm = lane & 15, ksl = lane >> 4;
  const int wcol = w * 32;

  __shared__ f16 Rh[32][40], Rl[32][40];   // padded, ds_write path
  __shared__ f16 Uh[4096], Ul[4096];       // linear + swizzle, gll path

  const int s0 = w * 128 + lane, s1 = s0 + 64;
  const int r0s = s0 >> 2, k0s = (s0 & 3) ^ ((r0s >> 1) & 3);
  const int r1s = s1 >> 2, k1s = (s1 & 3) ^ ((r1s >> 1) & 3);
  const u32 db0 = (u32)w * 2048u, db1 = db0 + 1024u;
  const int kswz = (ksl ^ ((lm >> 1) & 3)) * 8;

  float* __restrict__ G = (float*)(ws + OFF_G) + (size_t)ci * BATCH * NC;
  const f16* __restrict__ H1h = (const f16*)(ws + OFF_HHI + (size_t)((d + 2) % 3) * HPLANE);
  const f16* __restrict__ H1l = (const f16*)(ws + OFF_HLO + (size_t)((d + 2) % 3) * HPLANE);
  const f16* __restrict__ H2h = (const f16*)(ws + OFF_HHI + (size_t)((d + 1) % 3) * HPLANE);
  const f16* __restrict__ H2l = (const f16*)(ws + OFF_HLO + (size_t)((d + 1) % 3) * HPLANE);
  f16* __restrict__ Hoh = (f16*)(ws + OFF_HHI + (size_t)(d % 3) * HPLANE);
  f16* __restrict__ Hol = (f16*)(ws + OFF_HLO + (size_t)(d % 3) * HPLANE);
  const f16* __restrict__ UhT = (const f16*)(ws + OFF_UH);
  const f16* __restrict__ UlT = (const f16*)(ws + OFF_UL);
  const bool vt = (i > 0), vlf = (j > 0), vd = (i > 0 && j > 0);

  f32x4 acc[2][2];
#pragma unroll
  for (int mi = 0; mi < 2; mi++)
#pragma unroll
    for (int ni = 0; ni < 2; ni++)
#pragma unroll
      for (int r = 0; r < 4; r++) acc[mi][ni][r] = 0.f;

  const int sr = t >> 3, sk = (t & 7) * 4;   // rh staging: row sr, k sk..sk+3

  for (int kt = 0; kt < 12; kt++) {
    const f16 *ph, *pl; int hrow; bool ok;
    if (kt < 4)      { ph = H1h; pl = H1l; hrow = i;     ok = vlf; }  // h_left
    else if (kt < 8) { ph = H1h; pl = H1l; hrow = i - 1; ok = vt; }   // h_top
    else             { ph = H2h; pl = H2l; hrow = i - 1; ok = vd; }   // h_diag
    if (!ok) continue;
    {
      const int b = b0 + sr;
      const f32x4 g = *(const f32x4*)&G[(size_t)b * NC + kt * 32 + sk];
      const size_t hx = ((size_t)hrow * BATCH + b) * UNITS + (kt & 3) * 32 + sk;
      const half4 h4 = *(const half4*)(ph + hx);
      const half4 l4 = *(const half4*)(pl + hx);
      half4 oh, ol;
#pragma unroll
      for (int q = 0; q < 4; q++) {
        const float rv = 1.f / (1.f + __expf(-g[q]));
        const float v = rv * ((float)h4[q] + (float)l4[q]);
        const f16 h = (f16)v;
        oh[q] = h; ol[q] = (f16)(v - (float)h);
      }
      *(half4*)&Rh[sr][sk] = oh;
      *(half4*)&Rl[sr][sk] = ol;
    }
    {
      const size_t ub = (size_t)kt * 32;
      gll16(UhT + ub + r0s * KU + k0s * 8, (char*)Uh + db0);
      gll16(UhT + ub + r1s * KU + k1s * 8, (char*)Uh + db1);
      gll16(UlT + ub + r0s * KU + k0s * 8, (char*)Ul + db0);
      gll16(UlT + ub + r1s * KU + k1s * 8, (char*)Ul + db1);
    }
    __syncthreads();

    half8 afh[2], afl[2], bfh[2], bfl[2];
#pragma unroll
    for (int mi = 0; mi < 2; mi++) {
      afh[mi] = *(const half8*)&Rh[mi * 16 + lm][ksl * 8];
      afl[mi] = *(const half8*)&Rl[mi * 16 + lm][ksl * 8];
    }
#pragma unroll
    for (int ni = 0; ni < 2; ni++) {
      const int ro = (wcol + ni * 16 + lm) * 32 + kswz;
      bfh[ni] = *(const half8*)&Uh[ro];
      bfl[ni] = *(const half8*)&Ul[ro];
    }
#pragma unroll
    for (int mi = 0; mi < 2; mi++)
#pragma unroll
      for (int ni = 0; ni < 2; ni++) {
        acc[mi][ni] = __builtin_amdgcn_mfma_f32_16x16x32_f16(afh[mi], bfh[ni], acc[mi][ni], 0, 0, 0);
        acc[mi][ni] = __builtin_amdgcn_mfma_f32_16x16x32_f16(afl[mi], bfh[ni], acc[mi][ni], 0, 0, 0);
        acc[mi][ni] = __builtin_amdgcn_mfma_f32_16x16x32_f16(afh[mi], bfl[ni], acc[mi][ni], 0, 0, 0);
      }
    __syncthreads();
  }

  // ---- epilogue
#pragma unroll
  for (int mi = 0; mi < 2; mi++)
#pragma unroll
    for (int r = 0; r < 4; r++) {
      const int b = b0 + mi * 16 + ksl * 4 + r;
      const float* __restrict__ Gr = G + (size_t)b * NC;
      const size_t ho  = ((size_t)i * BATCH + b) * UNITS;        // out & h_left row
      const size_t htb = ((size_t)(i - 1) * BATCH + b) * UNITS;  // h_top / h_diag row
#pragma unroll
      for (int ni = 0; ni < 2; ni++) {
        const int u = wcol + ni * 16 + lm;
        const float zi = Gr[384 + u], zl = Gr[512 + u], zt = Gr[640 + u], zd = Gr[768 + u];
        const float mm = fmaxf(fmaxf(zi, zl), fmaxf(zt, zd));
        const float ei = __expf(zi - mm), el = __expf(zl - mm),
                    et = __expf(zt - mm), ed = __expf(zd - mm);
        const float inv = 1.f / (ei + el + et + ed);
        const float hl = vlf ? (float)H1h[ho + u] + (float)H1l[ho + u] : 0.f;
        const float ht = vt  ? (float)H1h[htb + u] + (float)H1l[htb + u] : 0.f;
        const float hd = vd  ? (float)H2h[htb + u] + (float)H2l[htb + u] : 0.f;
        const float hh = fast_tanh(Gr[896 + u] + acc[mi][ni][r]);
        const float h = (el * hl + et * ht + ed * hd + ei * hh) * inv;
        const f16 hhi = (f16)h;
        Hoh[ho + u] = hhi;
        Hol[ho + u] = (f16)(h - (float)hhi);
      }
    }
}

// ---------------------------------------------------------------------------
__global__ __launch_bounds__(256) void copy_kernel(const char* __restrict__ ws,
                                                   float* __restrict__ out) {
  int idx = blockIdx.x * 256 + threadIdx.x;   // 0..32767 = b*128+u
  // h(63,63) on diagonal 126 -> slot 126%3==0, row 63
  const f16* Hh = (const f16*)(ws + OFF_HHI);
  const f16* Hl = (const f16*)(ws + OFF_HLO);
  const size_t o = (size_t)63 * BATCH * UNITS + idx;
  out[idx] = (float)Hh[o] + (float)Hl[o];
}

// ---------------------------------------------------------------------------
extern "C" void kernel_launch(void* const* d_in, const int* in_sizes, int n_in,
                              void* d_out, int out_size, void* d_ws, size_t ws_size,
                              hipStream_t stream) {
  const float* inputs = (const float*)d_in[0];
  const float* wr     = (const float*)d_in[1];
  const float* br     = (const float*)d_in[2];
  const float* wz     = (const float*)d_in[3];
  const float* bz     = (const float*)d_in[4];
  const float* w_ij   = (const float*)d_in[5];
  const float* b_ij   = (const float*)d_in[6];
  const float* Umat   = (const float*)d_in[7];
  char* ws = (char*)d_ws;

  prep_kernel<<<dim3(1456), dim3(256), 0, stream>>>(
      wr, br, wz, bz, w_ij, b_ij, Umat, ws);

  for (int d = 0; d < 127; d++) {
    int i0 = d > 63 ? d - 63 : 0;
    int i1 = d < 63 ? d : 63;
    int nc = i1 - i0 + 1;
    gemm_kernel<<<dim3(nc, 16), dim3(256), 0, stream>>>(inputs, ws, d, i0);
    gate_kernel<<<dim3(nc, 8), dim3(256), 0, stream>>>(ws, d, i0);
  }

  copy_kernel<<<dim3(128), dim3(256), 0, stream>>>(ws, (float*)d_out);
}